// Round 3
// baseline (1143.397 us; speedup 1.0000x reference)
//
#include <hip/hip_runtime.h>

// ---------------------------------------------------------------------------
// PlanStructuredNetwork — round 5.
//   R4 post-mortem: skew regressed (787->856): LDS 46.6KB cut blocks/CU 4->3
//   (occ 29.6%), MfmaUtil DROPPED. Lesson: perf ~ resident waves; shrink
//   resources. R5:
//   * all input staging LDS removed: L1 B-frags are per-lane loads straight
//     to regs (R2-verified pattern, single PF buffer). No gload_lds, no
//     manual vmcnt — compiler-counted loads stay in flight across raw
//     s_barriers (only __syncthreads drains).
//   * 2 barriers/tile: phase A = L1(t) || L3(t-1)+store; phase B = L2(t).
//     h1 single, h2 parity-buffered. LDS = 26.4KB both leaf and join.
//   * biases in LDS; leaf launch_bounds(256,4) (~120 regs), join (256,3)
//     (72 regs of weights won't fit 128).
//   * tail levels nlev=16..1 fused into one kernel (2 batches/block,
//     cur handoff in LDS) — removes 4 dependent tiny launches.
//   * s_setprio(1) around L2 MFMA cluster.
// ws: 114688 B weights + 128 MB curA + 64 MB curB.
// ---------------------------------------------------------------------------

typedef _Float16 f16;
typedef _Float16 f16x8 __attribute__((ext_vector_type(8)));
typedef _Float16 f16x4 __attribute__((ext_vector_type(4)));
typedef float    f32x4 __attribute__((ext_vector_type(4)));

#define MFMA16(a, b, c) __builtin_amdgcn_mfma_f32_16x16x32_f16((a), (b), (c), 0, 0, 0)
#define LGKM0    asm volatile("s_waitcnt lgkmcnt(0)" ::: "memory")
#define BARRIER() do { __builtin_amdgcn_s_barrier(); __builtin_amdgcn_sched_barrier(0); } while (0)

// ws element offsets (f16) of transposed weights W^T[m][k]
#define OFF_S1 0       // [128][32]
#define OFF_S2 4096    // [128][128]
#define OFF_S3 20480   // [32][128]
#define OFF_J1 24576   // [128][96]
#define OFF_J2 36864   // [128][128]
#define OFF_J3 53248   // [32][128]
#define W_TOTAL 57344
#define CURA_BYTE_OFF 114688   // = W_TOTAL*2

__global__ void prep_weights(const float* __restrict__ sW1,
                             const float* __restrict__ sW2,
                             const float* __restrict__ sW3,
                             const float* __restrict__ jW1,
                             const float* __restrict__ jW2,
                             const float* __restrict__ jW3,
                             f16* __restrict__ wbuf)
{
    int idx = blockIdx.x * 256 + threadIdx.x;
    if (idx >= W_TOTAL) return;
    const float* W;
    int off, M, K;
    if (idx < OFF_S2)      { off = OFF_S1; M = 128; K = 32;  W = sW1; }
    else if (idx < OFF_S3) { off = OFF_S2; M = 128; K = 128; W = sW2; }
    else if (idx < OFF_J1) { off = OFF_S3; M = 32;  K = 128; W = sW3; }
    else if (idx < OFF_J2) { off = OFF_J1; M = 128; K = 96;  W = jW1; }
    else if (idx < OFF_J3) { off = OFF_J2; M = 128; K = 128; W = jW2; }
    else                   { off = OFF_J3; M = 32;  K = 128; W = jW3; }
    int r = idx - off;
    int m = r / K;
    int k = r - m * K;
    wbuf[idx] = (f16)W[(size_t)k * M + m];   // W^T[m][k] = W[k][m]
}

// Fused 3-layer MLP level, L3-skewed 2-barrier loop. Block = 256 threads =
// 4 waves; 32 rows (2 groups of 16) per tile. Wave w owns M-rows
// [32w,32w+32) of layers 1/2; layer 3: wave w -> group (w&1), M-half (w>>1).
template <bool LEAF>
__global__ __launch_bounds__(256, LEAF ? 4 : 3)
void mlp_level(const float* __restrict__ feats,
               const f16*   __restrict__ cur_in,
               f16*         __restrict__ cur_out,
               const f16*   __restrict__ W1t,
               const f16*   __restrict__ W2t,
               const f16*   __restrict__ W3t,
               const float* __restrict__ b1,
               const float* __restrict__ b2,
               const float* __restrict__ b3,
               int log2n, int foff, int nt)
{
    constexpr int K1  = LEAF ? 32 : 96;
    constexpr int NK1 = LEAF ? 1 : 3;

    // h rows: 128 f16 (256B), 16B-chunk XOR swizzle by (row&7) (R4-verified)
    __shared__ __align__(16) f16   h1[32 * 128];
    __shared__ __align__(16) f16   h2[2][32 * 128];
    __shared__ __align__(16) float bias_lds[288];   // b1[128] b2[128] b3[32]

    const int tid  = threadIdx.x;
    const int wave = tid >> 6;
    const int lane = tid & 63;
    const int n    = lane & 15;
    const int q    = lane >> 4;
    const int n7   = n & 7;
    const int mrow = 32 * wave;
    const int l3g  = wave & 1;
    const int l3h  = wave >> 1;

    if (tid < 128) bias_lds[tid] = b1[tid];
    else           bias_lds[tid] = b2[tid - 128];
    if (tid < 32)  bias_lds[256 + tid] = b3[tid];

    // ---- resident weights (A[m][k]; m = mrow + 16*mt + n, k = 32*ks+8*q+j)
    f16x8 A1[2][NK1], A2[2][4], A3[4];
#pragma unroll
    for (int mt = 0; mt < 2; ++mt)
#pragma unroll
        for (int ks = 0; ks < NK1; ++ks)
            A1[mt][ks] = *(const f16x8*)(W1t + (size_t)(mrow + 16 * mt + n) * K1 + 32 * ks + 8 * q);
#pragma unroll
    for (int mt = 0; mt < 2; ++mt)
#pragma unroll
        for (int ks = 0; ks < 4; ++ks)
            A2[mt][ks] = *(const f16x8*)(W2t + (size_t)(mrow + 16 * mt + n) * 128 + 32 * ks + 8 * q);
#pragma unroll
    for (int ks = 0; ks < 4; ++ks)
        A3[ks] = *(const f16x8*)(W3t + (size_t)(16 * l3h + n) * 128 + 32 * ks + 8 * q);

    LGKM0; BARRIER();   // bias_lds visible to all waves

    // ---- per-lane input fragments (registers, 1 tile ahead)
    struct PF { f32x4 fa[2], fb[2]; f16x8 cl[2], cr[2]; };  // cl/cr dead for LEAF
    auto load_pf = [&](int g0, PF& p) {
#pragma unroll
        for (int g = 0; g < 2; ++g) {
            int gr = g0 + 16 * g + n;
            const float* frow;
            if constexpr (LEAF) {
                frow = feats + (size_t)gr * 32;
            } else {
                int bb = gr >> log2n;
                int ii = gr & ((1 << log2n) - 1);
                frow = feats + ((size_t)bb * 1023 + foff + ii) * 32;
            }
            p.fa[g] = *(const f32x4*)(frow + 8 * q);
            p.fb[g] = *(const f32x4*)(frow + 8 * q + 4);
            if constexpr (!LEAF) {
                p.cl[g] = *(const f16x8*)(cur_in + (size_t)(2 * gr) * 32 + 8 * q);
                p.cr[g] = *(const f16x8*)(cur_in + (size_t)(2 * gr) * 32 + 32 + 8 * q);
            }
        }
    };

    auto doL1 = [&](const PF& p) {
        f32x4 C[2][2];
#pragma unroll
        for (int mt = 0; mt < 2; ++mt) {
            f32x4 bv = *(const f32x4*)&bias_lds[mrow + 16 * mt + 4 * q];
            C[0][mt] = bv; C[1][mt] = bv;
        }
#pragma unroll
        for (int g = 0; g < 2; ++g) {
            f16x8 Bf;
#pragma unroll
            for (int j = 0; j < 4; ++j) { Bf[j] = (f16)p.fa[g][j]; Bf[4 + j] = (f16)p.fb[g][j]; }
#pragma unroll
            for (int mt = 0; mt < 2; ++mt) C[g][mt] = MFMA16(A1[mt][0], Bf, C[g][mt]);
            if constexpr (!LEAF) {
#pragma unroll
                for (int mt = 0; mt < 2; ++mt) C[g][mt] = MFMA16(A1[mt][1], p.cl[g], C[g][mt]);
#pragma unroll
                for (int mt = 0; mt < 2; ++mt) C[g][mt] = MFMA16(A1[mt][2], p.cr[g], C[g][mt]);
            }
        }
#pragma unroll
        for (int g = 0; g < 2; ++g)
#pragma unroll
            for (int mt = 0; mt < 2; ++mt) {
                f16x4 pk;
                pk[0] = (f16)fmaxf(C[g][mt][0], 0.0f);
                pk[1] = (f16)fmaxf(C[g][mt][1], 0.0f);
                pk[2] = (f16)fmaxf(C[g][mt][2], 0.0f);
                pk[3] = (f16)fmaxf(C[g][mt][3], 0.0f);
                const int ch = 4 * wave + 2 * mt + (q >> 1);
                *(f16x4*)&h1[(16 * g + n) * 128 + ((ch ^ n7) << 3) + 4 * (q & 1)] = pk;
            }
    };

    auto doL2 = [&](int t) {
        const int hb = t & 1;
        f32x4 C[2][2];
#pragma unroll
        for (int mt = 0; mt < 2; ++mt) {
            f32x4 bv = *(const f32x4*)&bias_lds[128 + mrow + 16 * mt + 4 * q];
            C[0][mt] = bv; C[1][mt] = bv;
        }
        __builtin_amdgcn_s_setprio(1);
#pragma unroll
        for (int ks = 0; ks < 4; ++ks)
#pragma unroll
            for (int g = 0; g < 2; ++g) {
                f16x8 Bf = *(const f16x8*)&h1[(16 * g + n) * 128 + (((4 * ks + q) ^ n7) << 3)];
#pragma unroll
                for (int mt = 0; mt < 2; ++mt) C[g][mt] = MFMA16(A2[mt][ks], Bf, C[g][mt]);
            }
        __builtin_amdgcn_s_setprio(0);
#pragma unroll
        for (int g = 0; g < 2; ++g)
#pragma unroll
            for (int mt = 0; mt < 2; ++mt) {
                f16x4 pk;
                pk[0] = (f16)fmaxf(C[g][mt][0], 0.0f);
                pk[1] = (f16)fmaxf(C[g][mt][1], 0.0f);
                pk[2] = (f16)fmaxf(C[g][mt][2], 0.0f);
                pk[3] = (f16)fmaxf(C[g][mt][3], 0.0f);
                const int ch = 4 * wave + 2 * mt + (q >> 1);
                *(f16x4*)&h2[hb][(16 * g + n) * 128 + ((ch ^ n7) << 3) + 4 * (q & 1)] = pk;
            }
    };

    auto doL3 = [&](int t, int g0) {
        const int hb = t & 1;
        f32x4 C3 = *(const f32x4*)&bias_lds[256 + 16 * l3h + 4 * q];
#pragma unroll
        for (int ks = 0; ks < 4; ++ks) {
            f16x8 Bf = *(const f16x8*)&h2[hb][(16 * l3g + n) * 128 + (((4 * ks + q) ^ n7) << 3)];
            C3 = MFMA16(A3[ks], Bf, C3);
        }
        f16x4 pk;
        pk[0] = (f16)C3[0]; pk[1] = (f16)C3[1]; pk[2] = (f16)C3[2]; pk[3] = (f16)C3[3];
        *(f16x4*)(cur_out + (size_t)(g0 + 16 * l3g + n) * 32 + 16 * l3h + 4 * q) = pk;
    };

    const int stride = gridDim.x * 32;
    const int base   = blockIdx.x * 32;

    PF p;
    load_pf(base, p);
    for (int t = 0; t < nt; ++t) {
        const int g0 = base + t * stride;
        PF pn;
        if (t + 1 < nt) load_pf(g0 + stride, pn);     // in flight across barriers
        doL1(p);                                      // -> h1 (fenced by prev B-barrier)
        if (t > 0) doL3(t - 1, g0 - stride);          // h2[(t-1)&1] -> global
        LGKM0; BARRIER();                             // h1 visible
        doL2(t);                                      // h1 -> h2[t&1]
        LGKM0; BARRIER();                             // h2 visible
        if (t + 1 < nt) p = pn;
    }
    doL3(nt - 1, base + (nt - 1) * stride);
}

// ---- fused tail: levels nlev=16,8,4,2,1 for 2 batches per block -----------
__global__ __launch_bounds__(256, 2)
void mlp_tail(const float* __restrict__ feats,
              const f16*   __restrict__ cur_in,     // output of nlev=32 level
              float*       __restrict__ out_final,
              const f16*   __restrict__ W1t,
              const f16*   __restrict__ W2t,
              const f16*   __restrict__ W3t,
              const float* __restrict__ b1,
              const float* __restrict__ b2,
              const float* __restrict__ b3)
{
    __shared__ __align__(16) f16   h1[32 * 128];
    __shared__ __align__(16) f16   h2[32 * 128];
    __shared__ __align__(16) f16   cur_lds[32 * 32];
    __shared__ __align__(16) float bias_lds[288];

    const int tid  = threadIdx.x;
    const int wave = tid >> 6;
    const int lane = tid & 63;
    const int n    = lane & 15;
    const int q    = lane >> 4;
    const int n7   = n & 7;
    const int mrow = 32 * wave;
    const int l3g  = wave & 1;
    const int l3h  = wave >> 1;
    const int b0   = blockIdx.x * 2;

    if (tid < 128) bias_lds[tid] = b1[tid];
    else           bias_lds[tid] = b2[tid - 128];
    if (tid < 32)  bias_lds[256 + tid] = b3[tid];

    f16x8 A1[2][3], A2[2][4], A3[4];
#pragma unroll
    for (int mt = 0; mt < 2; ++mt)
#pragma unroll
        for (int ks = 0; ks < 3; ++ks)
            A1[mt][ks] = *(const f16x8*)(W1t + (size_t)(mrow + 16 * mt + n) * 96 + 32 * ks + 8 * q);
#pragma unroll
    for (int mt = 0; mt < 2; ++mt)
#pragma unroll
        for (int ks = 0; ks < 4; ++ks)
            A2[mt][ks] = *(const f16x8*)(W2t + (size_t)(mrow + 16 * mt + n) * 128 + 32 * ks + 8 * q);
#pragma unroll
    for (int ks = 0; ks < 4; ++ks)
        A3[ks] = *(const f16x8*)(W3t + (size_t)(16 * l3h + n) * 128 + 32 * ks + 8 * q);

    LGKM0; BARRIER();

    int nlev = 16, lg = 4, fo = 992;
    for (int lev = 0; lev < 5; ++lev) {
        const int rows_t = 2 * nlev;
        // ---- per-lane inputs (clamped addressing; invalid rows finite garbage)
        f32x4 fa[2], fb[2];
        f16x8 cl[2], cr[2];
#pragma unroll
        for (int g = 0; g < 2; ++g) {
            int r   = 16 * g + n;
            int sel = (r >> lg) & 1;
            int i   = r & (nlev - 1);
            int rc  = sel * nlev + i;                 // == r when valid, always in-range
            const float* frow = feats + ((size_t)(b0 + sel) * 1023 + fo + i) * 32;
            fa[g] = *(const f32x4*)(frow + 8 * q);
            fb[g] = *(const f32x4*)(frow + 8 * q + 4);
            if (lev == 0) {
                int gr = (b0 + sel) * 16 + i;
                cl[g] = *(const f16x8*)(cur_in + (size_t)(2 * gr) * 32 + 8 * q);
                cr[g] = *(const f16x8*)(cur_in + (size_t)(2 * gr) * 32 + 32 + 8 * q);
            } else {
                cl[g] = *(const f16x8*)&cur_lds[(2 * rc) * 32 + 8 * q];
                cr[g] = *(const f16x8*)&cur_lds[(2 * rc) * 32 + 32 + 8 * q];
            }
        }
        // ---- layer 1 -> h1
        {
            f32x4 C[2][2];
#pragma unroll
            for (int mt = 0; mt < 2; ++mt) {
                f32x4 bv = *(const f32x4*)&bias_lds[mrow + 16 * mt + 4 * q];
                C[0][mt] = bv; C[1][mt] = bv;
            }
#pragma unroll
            for (int g = 0; g < 2; ++g) {
                f16x8 Bf;
#pragma unroll
                for (int j = 0; j < 4; ++j) { Bf[j] = (f16)fa[g][j]; Bf[4 + j] = (f16)fb[g][j]; }
#pragma unroll
                for (int mt = 0; mt < 2; ++mt) C[g][mt] = MFMA16(A1[mt][0], Bf, C[g][mt]);
#pragma unroll
                for (int mt = 0; mt < 2; ++mt) C[g][mt] = MFMA16(A1[mt][1], cl[g], C[g][mt]);
#pragma unroll
                for (int mt = 0; mt < 2; ++mt) C[g][mt] = MFMA16(A1[mt][2], cr[g], C[g][mt]);
            }
#pragma unroll
            for (int g = 0; g < 2; ++g)
#pragma unroll
                for (int mt = 0; mt < 2; ++mt) {
                    f16x4 pk;
                    pk[0] = (f16)fmaxf(C[g][mt][0], 0.0f);
                    pk[1] = (f16)fmaxf(C[g][mt][1], 0.0f);
                    pk[2] = (f16)fmaxf(C[g][mt][2], 0.0f);
                    pk[3] = (f16)fmaxf(C[g][mt][3], 0.0f);
                    const int ch = 4 * wave + 2 * mt + (q >> 1);
                    *(f16x4*)&h1[(16 * g + n) * 128 + ((ch ^ n7) << 3) + 4 * (q & 1)] = pk;
                }
        }
        LGKM0; BARRIER();
        // ---- layer 2 -> h2
        {
            f32x4 C[2][2];
#pragma unroll
            for (int mt = 0; mt < 2; ++mt) {
                f32x4 bv = *(const f32x4*)&bias_lds[128 + mrow + 16 * mt + 4 * q];
                C[0][mt] = bv; C[1][mt] = bv;
            }
#pragma unroll
            for (int ks = 0; ks < 4; ++ks)
#pragma unroll
                for (int g = 0; g < 2; ++g) {
                    f16x8 Bf = *(const f16x8*)&h1[(16 * g + n) * 128 + (((4 * ks + q) ^ n7) << 3)];
#pragma unroll
                    for (int mt = 0; mt < 2; ++mt) C[g][mt] = MFMA16(A2[mt][ks], Bf, C[g][mt]);
                }
#pragma unroll
            for (int g = 0; g < 2; ++g)
#pragma unroll
                for (int mt = 0; mt < 2; ++mt) {
                    f16x4 pk;
                    pk[0] = (f16)fmaxf(C[g][mt][0], 0.0f);
                    pk[1] = (f16)fmaxf(C[g][mt][1], 0.0f);
                    pk[2] = (f16)fmaxf(C[g][mt][2], 0.0f);
                    pk[3] = (f16)fmaxf(C[g][mt][3], 0.0f);
                    const int ch = 4 * wave + 2 * mt + (q >> 1);
                    *(f16x4*)&h2[(16 * g + n) * 128 + ((ch ^ n7) << 3) + 4 * (q & 1)] = pk;
                }
        }
        LGKM0; BARRIER();
        // ---- layer 3 -> cur_lds / out_final
        {
            f32x4 C3 = *(const f32x4*)&bias_lds[256 + 16 * l3h + 4 * q];
#pragma unroll
            for (int ks = 0; ks < 4; ++ks) {
                f16x8 Bf = *(const f16x8*)&h2[(16 * l3g + n) * 128 + (((4 * ks + q) ^ n7) << 3)];
                C3 = MFMA16(A3[ks], Bf, C3);
            }
            if (nlev > 1) {
                int row = 16 * l3g + n;
                if (row < rows_t) {
                    f16x4 pk;
                    pk[0] = (f16)C3[0]; pk[1] = (f16)C3[1]; pk[2] = (f16)C3[2]; pk[3] = (f16)C3[3];
                    *(f16x4*)&cur_lds[row * 32 + 16 * l3h + 4 * q] = pk;
                }
            } else {
                if (l3g == 0 && l3h == 0 && q == 0 && n < 2)
                    out_final[b0 + n] = C3[0];
            }
        }
        LGKM0; BARRIER();
        fo += nlev;
        nlev >>= 1;
        --lg;
    }
}

extern "C" void kernel_launch(void* const* d_in, const int* in_sizes, int n_in,
                              void* d_out, int out_size, void* d_ws, size_t ws_size,
                              hipStream_t stream)
{
    const float* leaf_feats     = (const float*)d_in[0];
    const float* internal_feats = (const float*)d_in[1];
    const float* sW1 = (const float*)d_in[2];  const float* sb1 = (const float*)d_in[3];
    const float* sW2 = (const float*)d_in[4];  const float* sb2 = (const float*)d_in[5];
    const float* sW3 = (const float*)d_in[6];  const float* sb3 = (const float*)d_in[7];
    const float* jW1 = (const float*)d_in[8];  const float* jb1 = (const float*)d_in[9];
    const float* jW2 = (const float*)d_in[10]; const float* jb2 = (const float*)d_in[11];
    const float* jW3 = (const float*)d_in[12]; const float* jb3 = (const float*)d_in[13];

    f16* wbuf = (f16*)d_ws;
    f16* curA = (f16*)((char*)d_ws + CURA_BYTE_OFF);                 // 128 MB
    f16* curB = (f16*)((char*)d_ws + CURA_BYTE_OFF + 134217728);     // 64 MB

    prep_weights<<<(W_TOTAL + 255) / 256, 256, 0, stream>>>(
        sW1, sW2, sW3, jW1, jW2, jW3, wbuf);

    // leaf: 2048*1024 rows, 65536 tiles, nt = 32
    mlp_level<true><<<2048, 256, 0, stream>>>(
        leaf_feats, nullptr, curA,
        wbuf + OFF_S1, wbuf + OFF_S2, wbuf + OFF_S3,
        sb1, sb2, sb3,
        0, 0, 32);

    // join levels 512..32
    const f16* cin = curA;
    f16* cout = curB;
    int off = 0, lg = 9;
    for (int nlev = 512; nlev >= 32; nlev >>= 1, --lg) {
        int rows  = 2048 * nlev;
        int tiles = rows / 32;
        int grid  = tiles < 2048 ? tiles : 2048;
        int nt    = tiles / grid;
        mlp_level<false><<<grid, 256, 0, stream>>>(
            internal_feats, cin, cout,
            wbuf + OFF_J1, wbuf + OFF_J2, wbuf + OFF_J3,
            jb1, jb2, jb3,
            lg, off, nt);
        off += nlev;
        f16* t = cout; cout = (f16*)cin; cin = t;
    }

    // fused tail: levels 16..1 (off == 992 here), 2 batches per block
    mlp_tail<<<1024, 256, 0, stream>>>(
        internal_feats, cin, (float*)d_out,
        wbuf + OFF_J1, wbuf + OFF_J2, wbuf + OFF_J3,
        jb1, jb2, jb3);
}

// Round 5
// 796.678 us; speedup vs baseline: 1.4352x; 1.4352x over previous
//
#include <hip/hip_runtime.h>
#include <hip/hip_bf16.h>

// ---------------------------------------------------------------------------
// PlanStructuredNetwork — round 7 (= R6 resubmit; R6 bench timed out).
//   R4 (856) and R5 (1143) both lost to R3 (787): every restructuring that
//   grew LDS or replaced gload_lds staging with reg loads regressed. R6/R7 =
//   EXACT revert to the 787 kernel (gload_lds double-buffer staging, 3
//   barriers/tile, counted vmcnt) + two isolated resource-shrinking changes:
//   * leaf: biases -> LDS (-20 VGPR) and launch_bounds(256,4). R3's leaf sat
//     exactly at its (256,3) bound (occ 40%); LDS cap is 6 blocks.
//     Join path keeps register biases + bound 3 (codegen-identical to 787).
//   * tail levels nlev=16..1 fused into one kernel (R5-verified mlp_tail,
//     2 batches/block, subtree handoff in LDS) — removes 5 tiny dependent
//     launches. mlp_level handles 512..32 unchanged.
//   * prologue lgkmcnt(0) drains bias ds_writes before first barrier.
// ws: 114688 B weights + 128 MB curA + 64 MB curB (~192.1 MB).
// ---------------------------------------------------------------------------

typedef _Float16 f16;
typedef _Float16 f16x8 __attribute__((ext_vector_type(8)));
typedef _Float16 f16x4 __attribute__((ext_vector_type(4)));
typedef float    f32x4 __attribute__((ext_vector_type(4)));

#define MFMA16(a, b, c) __builtin_amdgcn_mfma_f32_16x16x32_f16((a), (b), (c), 0, 0, 0)
#define LGKM0    asm volatile("s_waitcnt lgkmcnt(0)" ::: "memory")

// ws element offsets (f16) of transposed weights W^T[m][k]
#define OFF_S1 0       // [128][32]
#define OFF_S2 4096    // [128][128]
#define OFF_S3 20480   // [32][128]
#define OFF_J1 24576   // [128][96]
#define OFF_J2 36864   // [128][128]
#define OFF_J3 53248   // [32][128]
#define W_TOTAL 57344
#define CURA_BYTE_OFF 114688   // = W_TOTAL*2

__global__ void prep_weights(const float* __restrict__ sW1,
                             const float* __restrict__ sW2,
                             const float* __restrict__ sW3,
                             const float* __restrict__ jW1,
                             const float* __restrict__ jW2,
                             const float* __restrict__ jW3,
                             f16* __restrict__ wbuf)
{
    int idx = blockIdx.x * 256 + threadIdx.x;
    if (idx >= W_TOTAL) return;
    const float* W;
    int off, M, K;
    if (idx < OFF_S2)      { off = OFF_S1; M = 128; K = 32;  W = sW1; }
    else if (idx < OFF_S3) { off = OFF_S2; M = 128; K = 128; W = sW2; }
    else if (idx < OFF_J1) { off = OFF_S3; M = 32;  K = 128; W = sW3; }
    else if (idx < OFF_J2) { off = OFF_J1; M = 128; K = 96;  W = jW1; }
    else if (idx < OFF_J3) { off = OFF_J2; M = 128; K = 128; W = jW2; }
    else                   { off = OFF_J3; M = 32;  K = 128; W = jW3; }
    int r = idx - off;
    int m = r / K;
    int k = r - m * K;
    wbuf[idx] = (f16)W[(size_t)k * M + m];   // W^T[m][k] = W[k][m]
}

__device__ __forceinline__ void gload16(const void* g, void* l)
{
    // async global->LDS, 16 B/lane; LDS dest = wave-uniform base + lane*16
    __builtin_amdgcn_global_load_lds(
        (const __attribute__((address_space(1))) void*)g,
        (__attribute__((address_space(3))) void*)l,
        16, 0, 0);
}

// Fused 3-layer MLP level (787us-verified structure). Block = 256 threads =
// 4 waves; 32 rows (2 groups of 16) per iteration. Wave w owns M-rows
// [32w,32w+32) of layers 1/2; layer 3 (M=32): wave w -> group (w&1),
// M-half (w>>1).
template <bool LEAF>
__global__ __launch_bounds__(256, LEAF ? 4 : 3)
void mlp_level(const float* __restrict__ feats,
               const f16*   __restrict__ cur_in,
               f16*         __restrict__ cur_out,
               const f16*   __restrict__ W1t,
               const f16*   __restrict__ W2t,
               const f16*   __restrict__ W3t,
               const float* __restrict__ b1,
               const float* __restrict__ b2,
               const float* __restrict__ b3,
               int rows, int log2n, int foff)
{
    constexpr int K1    = LEAF ? 32 : 96;
    constexpr int NK1   = LEAF ? 1 : 3;   // feats (+ curL + curR) K-steps
    constexpr int PITCH = 136;            // f16/row = 272 B (16B-mult, padded)

    __shared__ __align__(16) f16   h1[32 * PITCH];
    __shared__ __align__(16) f16   h2[32 * PITCH];
    __shared__ __align__(16) float fstage[2][32 * 32];              // 2 x 4 KB
    __shared__ __align__(16) f16   cstage[(LEAF ? 1 : 2)][32 * 64]; // join: 2 x 4 KB
    __shared__ __align__(16) float bias_lds[LEAF ? 288 : 1];        // leaf only

    const int tid  = threadIdx.x;
    const int wave = tid >> 6;
    const int lane = tid & 63;
    const int n    = lane & 15;   // node-local index (N dim of MFMA)
    const int q    = lane >> 4;
    const int n7   = n & 7;
    const int mrow = 32 * wave;   // L1/L2 M-slice base
    const int l3g  = wave & 1;    // L3: which group
    const int l3h  = wave >> 1;   // L3: which 16-row M-half

    // staging lane constants: wave w stages rows [8w, 8w+8); LDS dest is
    // linear (gload_lds), source chunk pre-swizzled so LDS slot s of row r
    // holds source chunk s^(r&7).
    const int srow   = (wave << 3) + (lane >> 3);
    const int schunk = (lane & 7) ^ (lane >> 3);

    // ---- leaf: biases -> LDS (frees ~20 VGPR for the 4-block bound)
    if constexpr (LEAF) {
        if (tid < 128) bias_lds[tid] = b1[tid];
        else           bias_lds[tid] = b2[tid - 128];
        if (tid < 32)  bias_lds[256 + tid] = b3[tid];
    }

    // ---- resident weights (A[m][k]; m = mrow + 16*mt + n, k = 32*ks+8*q+j)
    f16x8 A1[2][NK1], A2[2][4], A3[4];
#pragma unroll
    for (int mt = 0; mt < 2; ++mt)
#pragma unroll
        for (int ks = 0; ks < NK1; ++ks)
            A1[mt][ks] = *(const f16x8*)(W1t + (size_t)(mrow + 16 * mt + n) * K1 + 32 * ks + 8 * q);
#pragma unroll
    for (int mt = 0; mt < 2; ++mt)
#pragma unroll
        for (int ks = 0; ks < 4; ++ks)
            A2[mt][ks] = *(const f16x8*)(W2t + (size_t)(mrow + 16 * mt + n) * 128 + 32 * ks + 8 * q);
#pragma unroll
    for (int ks = 0; ks < 4; ++ks)
        A3[ks] = *(const f16x8*)(W3t + (size_t)(16 * l3h + n) * 128 + 32 * ks + 8 * q);

    // ---- bias fragments (join path: registers, as in the 787 version)
    f32x4 bf1[2], bf2[2], bf3;
    if constexpr (!LEAF) {
#pragma unroll
        for (int mt = 0; mt < 2; ++mt) {
            bf1[mt] = *(const f32x4*)(b1 + mrow + 16 * mt + 4 * q);
            bf2[mt] = *(const f32x4*)(b2 + mrow + 16 * mt + 4 * q);
        }
        bf3 = *(const f32x4*)(b3 + 16 * l3h + 4 * q);
    }

    // ---- async stage of one 32-row tile into LDS buffer sb.
    auto stage = [&](int tg0, int sb) {
        int gr = tg0 + srow;
        const float* fsrc;
        if constexpr (LEAF) {
            fsrc = feats + (size_t)gr * 32 + schunk * 4;
        } else {
            int bb = gr >> log2n;
            int ii = gr & ((1 << log2n) - 1);
            fsrc = feats + ((size_t)bb * 1023 + foff + ii) * 32 + schunk * 4;
        }
        gload16(fsrc, &fstage[sb][wave * 256]);
        if constexpr (!LEAF)
            gload16(cur_in + (size_t)gr * 64 + schunk * 8, &cstage[sb][wave * 512]);
    };

    const int stride = gridDim.x * 32;
    int g0 = blockIdx.x * 32;
    if (g0 >= rows) return;          // uniform per block; grid never exceeds

    int rb = 0;
    stage(g0, 0);                    // prologue: tile 0 in flight
    LGKM0;                           // leaf: bias ds_writes drained pre-barrier

    for (; g0 < rows; g0 += stride) {
        // issue next tile's stage first — stays in flight across barrier
        int gnext = g0 + stride;
        stage(gnext < rows ? gnext : g0, rb ^ 1);

        // wait for THIS tile's stage (issued last iter). Queue per wave:
        // [stage_i(K), (store_{i-1}: 0|1), stage_{i+1}(K)]; vmcnt(K) drains
        // stage_i (+ the store if present) for every wave shape. Never 0.
        if constexpr (LEAF) asm volatile("s_waitcnt vmcnt(1)" ::: "memory");
        else                asm volatile("s_waitcnt vmcnt(2)" ::: "memory");
        __builtin_amdgcn_s_barrier();      // all waves' quarters landed

        // ---------------- layer 1 ----------------
        f32x4 C[2][2];
#pragma unroll
        for (int g = 0; g < 2; ++g)
#pragma unroll
            for (int mt = 0; mt < 2; ++mt) {
                if constexpr (LEAF)
                    C[g][mt] = *(const f32x4*)&bias_lds[mrow + 16 * mt + 4 * q];
                else
                    C[g][mt] = bf1[mt];
            }

#pragma unroll
        for (int g = 0; g < 2; ++g) {
            const int r = 16 * g + n;
            // feats cols 8q..8q+7 (f32): chunks 2q, 2q+1, swizzled by r&7=n7
            f32x4 fa = *(const f32x4*)(&fstage[rb][r * 32 + (((2 * q)     ^ n7) * 4)]);
            f32x4 fb = *(const f32x4*)(&fstage[rb][r * 32 + (((2 * q + 1) ^ n7) * 4)]);
            f16x8 Bf;
#pragma unroll
            for (int j = 0; j < 4; ++j) {
                Bf[j]     = (f16)fa[j];
                Bf[4 + j] = (f16)fb[j];
            }
#pragma unroll
            for (int mt = 0; mt < 2; ++mt) C[g][mt] = MFMA16(A1[mt][0], Bf, C[g][mt]);
            if constexpr (!LEAF) {
                // left child = chunks 0..3 (chunk q), right = 4..7 (chunk 4+q)
                f16x8 cl = *(const f16x8*)(&cstage[rb][r * 64 + ((q       ^ n7) * 8)]);
                f16x8 cr = *(const f16x8*)(&cstage[rb][r * 64 + (((4 + q) ^ n7) * 8)]);
#pragma unroll
                for (int mt = 0; mt < 2; ++mt) C[g][mt] = MFMA16(A1[mt][1], cl, C[g][mt]);
#pragma unroll
                for (int mt = 0; mt < 2; ++mt) C[g][mt] = MFMA16(A1[mt][2], cr, C[g][mt]);
            }
        }
        // relu + pack -> h1[16g+n][mrow + 16mt + 4q + reg]
#pragma unroll
        for (int g = 0; g < 2; ++g)
#pragma unroll
            for (int mt = 0; mt < 2; ++mt) {
                f16x4 pk;
                pk[0] = (f16)fmaxf(C[g][mt][0], 0.0f);
                pk[1] = (f16)fmaxf(C[g][mt][1], 0.0f);
                pk[2] = (f16)fmaxf(C[g][mt][2], 0.0f);
                pk[3] = (f16)fmaxf(C[g][mt][3], 0.0f);
                *(f16x4*)(h1 + (16 * g + n) * PITCH + mrow + 16 * mt + 4 * q) = pk;
            }
        LGKM0;                              // h1 writes drained
        __builtin_amdgcn_s_barrier();

        // ---------------- layer 2 ----------------
#pragma unroll
        for (int g = 0; g < 2; ++g)
#pragma unroll
            for (int mt = 0; mt < 2; ++mt) {
                if constexpr (LEAF)
                    C[g][mt] = *(const f32x4*)&bias_lds[128 + mrow + 16 * mt + 4 * q];
                else
                    C[g][mt] = bf2[mt];
            }
#pragma unroll
        for (int ks = 0; ks < 4; ++ks)
#pragma unroll
            for (int g = 0; g < 2; ++g) {
                f16x8 Bf = *(const f16x8*)(h1 + (16 * g + n) * PITCH + 32 * ks + 8 * q);
#pragma unroll
                for (int mt = 0; mt < 2; ++mt) C[g][mt] = MFMA16(A2[mt][ks], Bf, C[g][mt]);
            }
#pragma unroll
        for (int g = 0; g < 2; ++g)
#pragma unroll
            for (int mt = 0; mt < 2; ++mt) {
                f16x4 pk;
                pk[0] = (f16)fmaxf(C[g][mt][0], 0.0f);
                pk[1] = (f16)fmaxf(C[g][mt][1], 0.0f);
                pk[2] = (f16)fmaxf(C[g][mt][2], 0.0f);
                pk[3] = (f16)fmaxf(C[g][mt][3], 0.0f);
                *(f16x4*)(h2 + (16 * g + n) * PITCH + mrow + 16 * mt + 4 * q) = pk;
            }
        LGKM0;                              // h2 writes drained
        __builtin_amdgcn_s_barrier();

        // ---------------- layer 3 (wave -> group l3g, M-half l3h) --------
        f32x4 C3;
        if constexpr (LEAF) C3 = *(const f32x4*)&bias_lds[256 + 16 * l3h + 4 * q];
        else                C3 = bf3;
#pragma unroll
        for (int ks = 0; ks < 4; ++ks) {
            f16x8 Bf = *(const f16x8*)(h2 + (16 * l3g + n) * PITCH + 32 * ks + 8 * q);
            C3 = MFMA16(A3[ks], Bf, C3);
        }
        {
            f16x4 pk;
            pk[0] = (f16)C3[0]; pk[1] = (f16)C3[1]; pk[2] = (f16)C3[2]; pk[3] = (f16)C3[3];
            *(f16x4*)(cur_out + (size_t)(g0 + 16 * l3g + n) * 32 + 16 * l3h + 4 * q) = pk;
        }
        // next-iter h1 writes are fenced by this iter's barriers

        rb ^= 1;
    }
}

// ---- fused tail: levels nlev=16,8,4,2,1 for 2 batches per block -----------
// (R5-verified correct: same absmax as the split-launch version.)
__global__ __launch_bounds__(256, 2)
void mlp_tail(const float* __restrict__ feats,
              const f16*   __restrict__ cur_in,     // output of nlev=32 level
              float*       __restrict__ out_final,
              const f16*   __restrict__ W1t,
              const f16*   __restrict__ W2t,
              const f16*   __restrict__ W3t,
              const float* __restrict__ b1,
              const float* __restrict__ b2,
              const float* __restrict__ b3)
{
    __shared__ __align__(16) f16   h1[32 * 128];
    __shared__ __align__(16) f16   h2[32 * 128];
    __shared__ __align__(16) f16   cur_lds[32 * 32];
    __shared__ __align__(16) float bias_lds[288];

    const int tid  = threadIdx.x;
    const int wave = tid >> 6;
    const int lane = tid & 63;
    const int n    = lane & 15;
    const int q    = lane >> 4;
    const int n7   = n & 7;
    const int mrow = 32 * wave;
    const int l3g  = wave & 1;
    const int l3h  = wave >> 1;
    const int b0   = blockIdx.x * 2;

    if (tid < 128) bias_lds[tid] = b1[tid];
    else           bias_lds[tid] = b2[tid - 128];
    if (tid < 32)  bias_lds[256 + tid] = b3[tid];

    f16x8 A1[2][3], A2[2][4], A3[4];
#pragma unroll
    for (int mt = 0; mt < 2; ++mt)
#pragma unroll
        for (int ks = 0; ks < 3; ++ks)
            A1[mt][ks] = *(const f16x8*)(W1t + (size_t)(mrow + 16 * mt + n) * 96 + 32 * ks + 8 * q);
#pragma unroll
    for (int mt = 0; mt < 2; ++mt)
#pragma unroll
        for (int ks = 0; ks < 4; ++ks)
            A2[mt][ks] = *(const f16x8*)(W2t + (size_t)(mrow + 16 * mt + n) * 128 + 32 * ks + 8 * q);
#pragma unroll
    for (int ks = 0; ks < 4; ++ks)
        A3[ks] = *(const f16x8*)(W3t + (size_t)(16 * l3h + n) * 128 + 32 * ks + 8 * q);

    LGKM0; __builtin_amdgcn_s_barrier();

    int nlev = 16, lg = 4, fo = 992;
    for (int lev = 0; lev < 5; ++lev) {
        const int rows_t = 2 * nlev;
        // ---- per-lane inputs (clamped addressing; invalid rows finite garbage)
        f32x4 fa[2], fb[2];
        f16x8 cl[2], cr[2];
#pragma unroll
        for (int g = 0; g < 2; ++g) {
            int r   = 16 * g + n;
            int sel = (r >> lg) & 1;
            int i   = r & (nlev - 1);
            int rc  = sel * nlev + i;                 // == r when valid, always in-range
            const float* frow = feats + ((size_t)(b0 + sel) * 1023 + fo + i) * 32;
            fa[g] = *(const f32x4*)(frow + 8 * q);
            fb[g] = *(const f32x4*)(frow + 8 * q + 4);
            if (lev == 0) {
                int gr = (b0 + sel) * 16 + i;
                cl[g] = *(const f16x8*)(cur_in + (size_t)(2 * gr) * 32 + 8 * q);
                cr[g] = *(const f16x8*)(cur_in + (size_t)(2 * gr) * 32 + 32 + 8 * q);
            } else {
                cl[g] = *(const f16x8*)&cur_lds[(2 * rc) * 32 + 8 * q];
                cr[g] = *(const f16x8*)&cur_lds[(2 * rc) * 32 + 32 + 8 * q];
            }
        }
        // ---- layer 1 -> h1
        {
            f32x4 C[2][2];
#pragma unroll
            for (int mt = 0; mt < 2; ++mt) {
                f32x4 bv = *(const f32x4*)&bias_lds[mrow + 16 * mt + 4 * q];
                C[0][mt] = bv; C[1][mt] = bv;
            }
#pragma unroll
            for (int g = 0; g < 2; ++g) {
                f16x8 Bf;
#pragma unroll
                for (int j = 0; j < 4; ++j) { Bf[j] = (f16)fa[g][j]; Bf[4 + j] = (f16)fb[g][j]; }
#pragma unroll
                for (int mt = 0; mt < 2; ++mt) C[g][mt] = MFMA16(A1[mt][0], Bf, C[g][mt]);
#pragma unroll
                for (int mt = 0; mt < 2; ++mt) C[g][mt] = MFMA16(A1[mt][1], cl[g], C[g][mt]);
#pragma unroll
                for (int mt = 0; mt < 2; ++mt) C[g][mt] = MFMA16(A1[mt][2], cr[g], C[g][mt]);
            }
#pragma unroll
            for (int g = 0; g < 2; ++g)
#pragma unroll
                for (int mt = 0; mt < 2; ++mt) {
                    f16x4 pk;
                    pk[0] = (f16)fmaxf(C[g][mt][0], 0.0f);
                    pk[1] = (f16)fmaxf(C[g][mt][1], 0.0f);
                    pk[2] = (f16)fmaxf(C[g][mt][2], 0.0f);
                    pk[3] = (f16)fmaxf(C[g][mt][3], 0.0f);
                    const int ch = 4 * wave + 2 * mt + (q >> 1);
                    *(f16x4*)&h1[(16 * g + n) * 128 + ((ch ^ n7) << 3) + 4 * (q & 1)] = pk;
                }
        }
        LGKM0; __builtin_amdgcn_s_barrier();
        // ---- layer 2 -> h2
        {
            f32x4 C[2][2];
#pragma unroll
            for (int mt = 0; mt < 2; ++mt) {
                f32x4 bv = *(const f32x4*)&bias_lds[128 + mrow + 16 * mt + 4 * q];
                C[0][mt] = bv; C[1][mt] = bv;
            }
#pragma unroll
            for (int ks = 0; ks < 4; ++ks)
#pragma unroll
                for (int g = 0; g < 2; ++g) {
                    f16x8 Bf = *(const f16x8*)&h1[(16 * g + n) * 128 + (((4 * ks + q) ^ n7) << 3)];
#pragma unroll
                    for (int mt = 0; mt < 2; ++mt) C[g][mt] = MFMA16(A2[mt][ks], Bf, C[g][mt]);
                }
#pragma unroll
            for (int g = 0; g < 2; ++g)
#pragma unroll
                for (int mt = 0; mt < 2; ++mt) {
                    f16x4 pk;
                    pk[0] = (f16)fmaxf(C[g][mt][0], 0.0f);
                    pk[1] = (f16)fmaxf(C[g][mt][1], 0.0f);
                    pk[2] = (f16)fmaxf(C[g][mt][2], 0.0f);
                    pk[3] = (f16)fmaxf(C[g][mt][3], 0.0f);
                    const int ch = 4 * wave + 2 * mt + (q >> 1);
                    *(f16x4*)&h2[(16 * g + n) * 128 + ((ch ^ n7) << 3) + 4 * (q & 1)] = pk;
                }
        }
        LGKM0; __builtin_amdgcn_s_barrier();
        // ---- layer 3 -> cur_lds / out_final
        {
            f32x4 C3 = *(const f32x4*)&bias_lds[256 + 16 * l3h + 4 * q];
#pragma unroll
            for (int ks = 0; ks < 4; ++ks) {
                f16x8 Bf = *(const f16x8*)&h2[(16 * l3g + n) * 128 + (((4 * ks + q) ^ n7) << 3)];
                C3 = MFMA16(A3[ks], Bf, C3);
            }
            if (nlev > 1) {
                int row = 16 * l3g + n;
                if (row < rows_t) {
                    f16x4 pk;
                    pk[0] = (f16)C3[0]; pk[1] = (f16)C3[1]; pk[2] = (f16)C3[2]; pk[3] = (f16)C3[3];
                    *(f16x4*)&cur_lds[row * 32 + 16 * l3h + 4 * q] = pk;
                }
            } else {
                if (l3g == 0 && l3h == 0 && q == 0 && n < 2)
                    out_final[b0 + n] = C3[0];
            }
        }
        LGKM0; __builtin_amdgcn_s_barrier();
        fo += nlev;
        nlev >>= 1;
        --lg;
    }
}

extern "C" void kernel_launch(void* const* d_in, const int* in_sizes, int n_in,
                              void* d_out, int out_size, void* d_ws, size_t ws_size,
                              hipStream_t stream)
{
    const float* leaf_feats     = (const float*)d_in[0];
    const float* internal_feats = (const float*)d_in[1];
    const float* sW1 = (const float*)d_in[2];  const float* sb1 = (const float*)d_in[3];
    const float* sW2 = (const float*)d_in[4];  const float* sb2 = (const float*)d_in[5];
    const float* sW3 = (const float*)d_in[6];  const float* sb3 = (const float*)d_in[7];
    const float* jW1 = (const float*)d_in[8];  const float* jb1 = (const float*)d_in[9];
    const float* jW2 = (const float*)d_in[10]; const float* jb2 = (const float*)d_in[11];
    const float* jW3 = (const float*)d_in[12]; const float* jb3 = (const float*)d_in[13];

    f16* wbuf = (f16*)d_ws;
    f16* curA = (f16*)((char*)d_ws + CURA_BYTE_OFF);                 // 128 MB
    f16* curB = (f16*)((char*)d_ws + CURA_BYTE_OFF + 134217728);     // 64 MB

    prep_weights<<<(W_TOTAL + 255) / 256, 256, 0, stream>>>(
        sW1, sW2, sW3, jW1, jW2, jW3, wbuf);

    // leaf: 2048*1024 rows, 65536 tiles of 32 rows
    mlp_level<true><<<2048, 256, 0, stream>>>(
        leaf_feats, nullptr, curA,
        wbuf + OFF_S1, wbuf + OFF_S2, wbuf + OFF_S3,
        sb1, sb2, sb3,
        2048 * 1024, 0, 0);

    // join levels 512..32
    const f16* cin = curA;
    f16* cout = curB;
    int off = 0, lg = 9;
    for (int nlev = 512; nlev >= 32; nlev >>= 1, --lg) {
        int rows  = 2048 * nlev;
        int iters = rows / 32;
        int grid  = iters < 2048 ? iters : 2048;
        mlp_level<false><<<grid, 256, 0, stream>>>(
            internal_feats, cin, cout,
            wbuf + OFF_J1, wbuf + OFF_J2, wbuf + OFF_J3,
            jb1, jb2, jb3,
            rows, lg, off);
        off += nlev;
        f16* t = cout; cout = (f16*)cin; cin = t;
    }

    // fused tail: levels 16..1 (off == 992 here), 2 batches per block
    mlp_tail<<<1024, 256, 0, stream>>>(
        internal_feats, cin, (float*)d_out,
        wbuf + OFF_J1, wbuf + OFF_J2, wbuf + OFF_J3,
        jb1, jb2, jb3);
}